// Round 2
// baseline (20965.556 us; speedup 1.0000x reference)
//
#include <hip/hip_runtime.h>

// Problem dims (fixed)
constexpr int BATCH = 64;
constexpr int SEQ   = 512;
constexpr int DIN   = 512;
constexpr int HID   = 512;
constexpr int LAY   = 2;
constexpr int G3    = 3 * HID;   // 1536

typedef __attribute__((ext_vector_type(8))) short bf16x8;  // 8 bf16 = 4 VGPRs (MFMA A/B frag)
typedef __attribute__((ext_vector_type(4))) float f32x4;   // MFMA C/D frag
typedef unsigned short u16;
typedef unsigned int   u32;

__device__ __forceinline__ u16 f2bf(float f) {
  union { float f; u32 u; } v; v.f = f;
  return (u16)((v.u + 0x7fffu + ((v.u >> 16) & 1u)) >> 16);  // round-nearest-even
}

struct Params {
  const float* input;     // [BATCH][SEQ][DIN]
  const float* enc_h;     // [LAY][BATCH][2*HID]
  const float* Wih[2];    // dir f/b: [LAY][G3][DIN]
  const float* Whh[2];    // [LAY][G3][HID]
  const float* bih[2];    // [LAY][G3]
  const float* bhh[2];    // [LAY][G3]
  float* out;             // [BATCH][SEQ][2H] ++ [LAY][BATCH][2H]
  u16* xin;               // [BATCH][SEQ][DIN] bf16
  u16* wih;               // [2][LAY][G3][DIN] bf16
  u16* whh;               // [2][LAY][G3][HID] bf16
  u16* out0;              // [2][SEQ][BATCH][HID] bf16 layer-0 outputs (scan order)
  u16* hbf;               // [2 parity][2 dir][BATCH][HID] bf16 h broadcast
  int* cnt;               // [LAY][2] monotonic barrier counters
};

// Barrier among the 32 WGs of one (layer,dir) cell. All 64 recurrence WGs are
// resident (64 blocks <= 256 CUs, regular launch => every WG gets a CU slot,
// spinning waves don't block placement of the rest). Agent-scope fences handle
// cross-XCD L2 visibility (G16).
__device__ __forceinline__ void cell_barrier(int* cnt, int target) {
  __syncthreads();  // __syncthreads drains vmcnt(0): this WG's h stores issued
  if (threadIdx.x == 0) {
    __threadfence();  // agent-scope release of our h stores
    __hip_atomic_fetch_add(cnt, 1, __ATOMIC_RELEASE, __HIP_MEMORY_SCOPE_AGENT);
    while (__hip_atomic_load(cnt, __ATOMIC_RELAXED, __HIP_MEMORY_SCOPE_AGENT) < target)
      __builtin_amdgcn_s_sleep(2);
    __threadfence();  // acquire: invalidate caches before re-reading h
  }
  __syncthreads();
}

// P0: fp32 -> bf16 conversions of input and weights; zero barrier counters.
__global__ __launch_bounds__(256) void convert_kernel(Params p) {
  const int gtid = blockIdx.x * 256 + threadIdx.x;
  const int nthr = gridDim.x * 256;
  for (int i = gtid; i < BATCH * SEQ * DIN; i += nthr) p.xin[i] = f2bf(p.input[i]);
  for (int d = 0; d < 2; ++d) {
    const float* s1 = p.Wih[d];
    u16* d1 = p.wih + (size_t)d * LAY * G3 * DIN;
    for (int i = gtid; i < LAY * G3 * DIN; i += nthr) d1[i] = f2bf(s1[i]);
    const float* s2 = p.Whh[d];
    u16* d2 = p.whh + (size_t)d * LAY * G3 * HID;
    for (int i = gtid; i < LAY * G3 * HID; i += nthr) d2[i] = f2bf(s2[i]);
  }
  if (gtid < 64) p.cnt[gtid] = 0;
}

// Recurrence for one layer, both directions concurrently. 64 WGs:
// dir = wg&1, 16-wide hidden slice = wg>>1. Each WG: 4 waves, wave = M-tile of
// 16 batch rows. Input-to-hidden GEMM fused into the step (no gi buffer).
// h master state fp32 in registers; bf16 double-buffered broadcast in hbf.
template<int LAYER>
__global__ __launch_bounds__(256, 2) void recur_kernel(Params p) {
  const int wg = blockIdx.x;      // 0..63
  const int dir   = wg & 1;
  const int slice = wg >> 1;      // 0..31
  const int j0    = slice * 16;
  const int wave  = threadIdx.x >> 6;
  const int lane  = threadIdx.x & 63;
  const int lq = lane >> 4, ln = lane & 15;
  const int j = j0 + ln;          // hidden column (C/D col = lane&15)

  u16* hb[2];  // parity buffers, layout [par][dir][B][H]
  hb[0] = p.hbf + (size_t)dir * BATCH * HID;
  hb[1] = p.hbf + (size_t)(2 + dir) * BATCH * HID;

  const u16* whh = p.whh + ((size_t)dir * LAY + LAYER) * G3 * HID;
  const u16* wih = p.wih + ((size_t)dir * LAY + LAYER) * G3 * DIN;
  const u16* brh[3];  // Whh B-frag rows (B stored [N][K], lane&15 = n)
  const u16* bri[3];  // Wih B-frag rows
  #pragma unroll
  for (int g = 0; g < 3; ++g) {
    brh[g] = whh + (size_t)(g * HID + j) * HID;
    bri[g] = wih + (size_t)(g * HID + j) * DIN;
  }
  const float* bih = p.bih[dir] + (size_t)LAYER * G3;
  const float* bhh = p.bhh[dir] + (size_t)LAYER * G3;
  const float b_r  = bih[j] + bhh[j];                    // combined (r gate)
  const float b_z  = bih[HID + j] + bhh[HID + j];        // combined (z gate)
  const float bi_n = bih[2 * HID + j];                   // n gate: keep separate
  const float bh_n = bhh[2 * HID + j];

  // init h (fp32 master in regs) + bf16 broadcast into parity 0
  float hreg[4];
  #pragma unroll
  for (int i = 0; i < 4; ++i) {
    const int m = wave * 16 + lq * 4 + i;   // C/D row = (lane>>4)*4 + reg
    hreg[i] = p.enc_h[((size_t)LAYER * BATCH + m) * (2 * HID) + (size_t)dir * HID + j];
    hb[0][(size_t)m * HID + j] = f2bf(hreg[i]);
  }
  int* cnt = p.cnt + LAYER * 2 + dir;
  cell_barrier(cnt, 32);  // init visible to all WGs of this cell

  const int am = wave * 16 + ln;  // A-frag row (m = lane&15 within M-tile)
  float* hsec = p.out + (size_t)BATCH * SEQ * 2 * HID;  // final-h section

  for (int t = 0; t < SEQ; ++t) {
    const u16* hread = hb[t & 1];
    u16* hwrite      = hb[(t + 1) & 1];
    const u16* ah = hread + (size_t)am * HID;
    const u16* ax;
    if (LAYER == 0) {
      const int tt = dir ? (SEQ - 1 - t) : t;
      ax = p.xin + ((size_t)am * SEQ + tt) * DIN;
    } else {
      ax = p.out0 + (((size_t)dir * SEQ + t) * BATCH + am) * HID;
    }

    f32x4 acch[3] = {}, accx[3] = {};
    #pragma unroll 4
    for (int k0 = 0; k0 < 512; k0 += 32) {
      const int koff = k0 + lq * 8;
      const bf16x8 a_h = *(const bf16x8*)(ah + koff);
      const bf16x8 a_x = *(const bf16x8*)(ax + koff);
      #pragma unroll
      for (int g = 0; g < 3; ++g) {
        acch[g] = __builtin_amdgcn_mfma_f32_16x16x32_bf16(
            a_h, *(const bf16x8*)(brh[g] + koff), acch[g], 0, 0, 0);
        accx[g] = __builtin_amdgcn_mfma_f32_16x16x32_bf16(
            a_x, *(const bf16x8*)(bri[g] + koff), accx[g], 0, 0, 0);
      }
    }

    #pragma unroll
    for (int i = 0; i < 4; ++i) {
      const int m = wave * 16 + lq * 4 + i;
      const float r = 1.f / (1.f + __expf(-(accx[0][i] + acch[0][i] + b_r)));
      const float z = 1.f / (1.f + __expf(-(accx[1][i] + acch[1][i] + b_z)));
      const float n = tanhf(accx[2][i] + bi_n + r * (acch[2][i] + bh_n));
      const float hnew = (1.f - z) * n + z * hreg[i];
      hreg[i] = hnew;
      hwrite[(size_t)m * HID + j] = f2bf(hnew);
      if (LAYER == 0) {
        p.out0[(((size_t)dir * SEQ + t) * BATCH + m) * HID + j] = f2bf(hnew);
      } else {
        const int tt = dir ? (SEQ - 1 - t) : t;
        p.out[((size_t)m * SEQ + tt) * (2 * HID) + (size_t)dir * HID + j] = hnew;
      }
      if (t == SEQ - 1)
        hsec[((size_t)LAYER * BATCH + m) * (2 * HID) + (size_t)dir * HID + j] = hnew;
    }
    if (t + 1 < SEQ) cell_barrier(cnt, 32 * (t + 2));
  }
}

extern "C" void kernel_launch(void* const* d_in, const int* in_sizes, int n_in,
                              void* d_out, int out_size, void* d_ws, size_t ws_size,
                              hipStream_t stream) {
  Params p;
  p.input  = (const float*)d_in[0];
  p.enc_h  = (const float*)d_in[1];
  p.Wih[0] = (const float*)d_in[2];
  p.Whh[0] = (const float*)d_in[3];
  p.bih[0] = (const float*)d_in[4];
  p.bhh[0] = (const float*)d_in[5];
  p.Wih[1] = (const float*)d_in[6];
  p.Whh[1] = (const float*)d_in[7];
  p.bih[1] = (const float*)d_in[8];
  p.bhh[1] = (const float*)d_in[9];
  p.out = (float*)d_out;

  uintptr_t base = (uintptr_t)d_ws;
  size_t off = 0;
  auto take = [&](size_t bytes) -> void* {
    void* r = (void*)(base + off);
    off += (bytes + 255) & ~(size_t)255;
    return r;
  };
  p.xin  = (u16*)take((size_t)BATCH * SEQ * DIN * 2);        // 33.6 MB
  p.wih  = (u16*)take((size_t)2 * LAY * G3 * DIN * 2);       //  6.3 MB
  p.whh  = (u16*)take((size_t)2 * LAY * G3 * HID * 2);       //  6.3 MB
  p.out0 = (u16*)take((size_t)2 * SEQ * BATCH * HID * 2);    // 67.1 MB
  p.hbf  = (u16*)take((size_t)2 * 2 * BATCH * HID * 2);      //  0.5 MB
  p.cnt  = (int*)take(256);
  if (off > ws_size) return;  // ~114 MB required

  convert_kernel<<<dim3(2048), dim3(256), 0, stream>>>(p);
  recur_kernel<0><<<dim3(64), dim3(256), 0, stream>>>(p);
  recur_kernel<1><<<dim3(64), dim3(256), 0, stream>>>(p);
}

// Round 4
// 8637.257 us; speedup vs baseline: 2.4273x; 2.4273x over previous
//
#include <hip/hip_runtime.h>

// Problem dims (fixed)
constexpr int BATCH = 64;
constexpr int SEQ   = 512;
constexpr int DIN   = 512;
constexpr int HID   = 512;
constexpr int LAY   = 2;
constexpr int G3    = 3 * HID;   // 1536
constexpr int KPAD  = 520;       // LDS k-stride pad (+8 elems): free 2-way bank aliasing

typedef __attribute__((ext_vector_type(8))) short bf16x8;  // MFMA A/B frag (4 VGPRs)
typedef __attribute__((ext_vector_type(4))) float f32x4;   // MFMA C/D frag
typedef unsigned short u16;
typedef unsigned int   u32;
typedef unsigned long long u64;

__device__ __forceinline__ u16 f2bf(float f) {
  union { float f; u32 u; } v; v.f = f;
  return (u16)((v.u + 0x7fffu + ((v.u >> 16) & 1u)) >> 16);  // RNE
}

// Agent-scope relaxed accesses: coherent at LLC (bypass non-coherent L1/L2),
// NO cache maintenance emitted (unlike __threadfence acquire -> buffer_inv,
// which was R2's 20 us/step killer).
__device__ __forceinline__ u64 ld_agent_u64(const u16* p) {
  return __hip_atomic_load((const u64*)p, __ATOMIC_RELAXED, __HIP_MEMORY_SCOPE_AGENT);
}
__device__ __forceinline__ bf16x8 ld_frag_agent(const u16* p) {
  union { u64 q[2]; bf16x8 f; } u;
  u.q[0] = ld_agent_u64(p);
  u.q[1] = ld_agent_u64(p + 4);
  return u.f;
}
__device__ __forceinline__ void st_agent_u16(u16* p, u16 v) {
  __hip_atomic_store(p, v, __ATOMIC_RELAXED, __HIP_MEMORY_SCOPE_AGENT);
}

struct Params {
  const float* input;     // [BATCH][SEQ][DIN]
  const float* enc_h;     // [LAY][BATCH][2*HID]
  const float* Wih[2];    // dir f/b: [LAY][G3][DIN]
  const float* Whh[2];    // [LAY][G3][HID]
  const float* bih[2];    // [LAY][G3]
  const float* bhh[2];    // [LAY][G3]
  float* out;             // [BATCH][SEQ][2H] ++ [LAY][BATCH][2H]
  u16* xin;               // [BATCH][SEQ][DIN] bf16
  u16* wih;               // [2dir][LAY][G3][DIN] bf16
  u16* whh;               // [2dir][LAY][G3][HID] bf16
  u16* out0;              // [2dir][SEQ][BATCH][HID] bf16 layer-0 outputs (scan order)
  u16* hbf;               // [LAY][2 parity][2 dir][BATCH][HID] bf16 h broadcast
  int* cnt;               // [LAY][2dir] monotonic barrier counters
};

__global__ __launch_bounds__(256) void convert_kernel(Params p) {
  const int gtid = blockIdx.x * 256 + threadIdx.x;
  const int nthr = gridDim.x * 256;
  for (int i = gtid; i < BATCH * SEQ * DIN; i += nthr) p.xin[i] = f2bf(p.input[i]);
  for (int d = 0; d < 2; ++d) {
    const float* s1 = p.Wih[d];
    u16* d1 = p.wih + (size_t)d * LAY * G3 * DIN;
    for (int i = gtid; i < LAY * G3 * DIN; i += nthr) d1[i] = f2bf(s1[i]);
    const float* s2 = p.Whh[d];
    u16* d2 = p.whh + (size_t)d * LAY * G3 * HID;
    for (int i = gtid; i < LAY * G3 * HID; i += nthr) d2[i] = f2bf(s2[i]);
  }
  if (gtid < 64) p.cnt[gtid] = 0;
}

// 128 WGs: wg>>6 = layer (pipelined: layer1 trails layer0 by one step),
// wg&1 = dir, (wg&63)>>1 = 16-wide hidden slice. 4 waves = 4 batch m-tiles.
// h master state fp32 in registers; bf16 double-buffered broadcast via LLC.
// Whh slice LDS-resident; Wih slice L1/L2-cached (no invalidation anymore).
// Counter protocol: each (layer,dir) counter is incremented by its 32 WGs at
// init and after EVERY step (layer 0 also signals after the last step, since
// layer 1's final dependency target is 32*(SEQ+1) = 32*513 — R3 deadlocked
// by skipping that final increment).
__global__ __launch_bounds__(256, 1) void recur_all(Params p) {
  const int wg    = blockIdx.x;     // 0..127
  const int layer = wg >> 6;
  const int cwg   = wg & 63;
  const int dir   = cwg & 1;
  const int slice = cwg >> 1;       // 0..31
  const int j0    = slice * 16;
  const int wave  = threadIdx.x >> 6;
  const int lane  = threadIdx.x & 63;
  const int lq = lane >> 4, ln = lane & 15;
  const int j = j0 + ln;            // hidden column (C/D col = lane&15)

  // ---- stage Whh slice into LDS: [gate][jj][k] padded ----
  __shared__ u16 lwhh[3][16][KPAD];   // 49,920 B
  {
    const u16* whh = p.whh + ((size_t)dir * LAY + layer) * G3 * HID;
    for (int idx = threadIdx.x; idx < 3 * 16 * 64; idx += 256) {
      const int k8 = idx & 63, row = idx >> 6;     // row = g*16+jj
      const int g = row >> 4, jj = row & 15;
      *(bf16x8*)&lwhh[g][jj][k8 * 8] =
          *(const bf16x8*)(whh + (size_t)(g * HID + j0 + jj) * HID + k8 * 8);
    }
  }

  u16* hbL = p.hbf + (size_t)layer * 2 * 2 * BATCH * HID;
  u16* hb[2] = { hbL + (size_t)dir * BATCH * HID,
                 hbL + (size_t)(2 + dir) * BATCH * HID };

  const u16* wih = p.wih + ((size_t)dir * LAY + layer) * G3 * DIN;
  const u16* bri[3];
  #pragma unroll
  for (int g = 0; g < 3; ++g) bri[g] = wih + (size_t)(g * HID + j) * DIN;

  const float* bih = p.bih[dir] + (size_t)layer * G3;
  const float* bhh = p.bhh[dir] + (size_t)layer * G3;
  const float b_r  = bih[j] + bhh[j];
  const float b_z  = bih[HID + j] + bhh[HID + j];
  const float bi_n = bih[2 * HID + j];
  const float bh_n = bhh[2 * HID + j];

  // init h (fp32 master) + bf16 broadcast into parity 0 (agent-scope)
  float hreg[4];
  #pragma unroll
  for (int i = 0; i < 4; ++i) {
    const int m = wave * 16 + lq * 4 + i;       // C/D row = (lane>>4)*4 + reg
    hreg[i] = p.enc_h[((size_t)layer * BATCH + m) * (2 * HID) + (size_t)dir * HID + j];
    st_agent_u16(&hb[0][(size_t)m * HID + j], f2bf(hreg[i]));
  }

  int* cnt_own = p.cnt + layer * 2 + dir;
  int* cnt_dep = p.cnt + dir;                   // layer-0's counter (same dir)

  __syncthreads();  // LDS staging done + all waves' init h stores drained (vmcnt 0)
  if (threadIdx.x == 0) {
    __hip_atomic_fetch_add(cnt_own, 1, __ATOMIC_RELEASE, __HIP_MEMORY_SCOPE_AGENT);
    while (__hip_atomic_load(cnt_own, __ATOMIC_RELAXED, __HIP_MEMORY_SCOPE_AGENT) < 32)
      __builtin_amdgcn_s_sleep(2);
    if (layer == 1)  // need out0[0]: layer0 step 0 complete
      while (__hip_atomic_load(cnt_dep, __ATOMIC_RELAXED, __HIP_MEMORY_SCOPE_AGENT) < 64)
        __builtin_amdgcn_s_sleep(2);
  }
  __syncthreads();

  const int am = wave * 16 + ln;                // A-frag row (lane&15 within M-tile)
  float* hsec = p.out + (size_t)BATCH * SEQ * 2 * HID;

  for (int t = 0; t < SEQ; ++t) {
    const u16* hread = hb[t & 1];
    u16* hwrite      = hb[(t + 1) & 1];
    const u16* ah = hread + (size_t)am * HID;
    const u16* ax = (layer == 0)
        ? p.xin + ((size_t)am * SEQ + (dir ? SEQ - 1 - t : t)) * DIN
        : p.out0 + (((size_t)dir * SEQ + t) * BATCH + am) * HID;

    f32x4 acch[3] = {}, accx[3] = {};
    #pragma unroll 4
    for (int k0 = 0; k0 < 512; k0 += 32) {
      const int koff = k0 + lq * 8;
      const bf16x8 a_h = ld_frag_agent(ah + koff);               // LLC-coherent
      const bf16x8 a_x = (layer == 0) ? *(const bf16x8*)(ax + koff)
                                      : ld_frag_agent(ax + koff);
      #pragma unroll
      for (int g = 0; g < 3; ++g) {
        acch[g] = __builtin_amdgcn_mfma_f32_16x16x32_bf16(
            a_h, *(const bf16x8*)&lwhh[g][ln][koff], acch[g], 0, 0, 0);
        accx[g] = __builtin_amdgcn_mfma_f32_16x16x32_bf16(
            a_x, *(const bf16x8*)(bri[g] + koff), accx[g], 0, 0, 0);
      }
    }

    #pragma unroll
    for (int i = 0; i < 4; ++i) {
      const int m = wave * 16 + lq * 4 + i;
      const float r = 1.f / (1.f + __expf(-(accx[0][i] + acch[0][i] + b_r)));
      const float z = 1.f / (1.f + __expf(-(accx[1][i] + acch[1][i] + b_z)));
      const float n = tanhf(accx[2][i] + bi_n + r * (acch[2][i] + bh_n));
      const float hnew = (1.f - z) * n + z * hreg[i];
      hreg[i] = hnew;
      if (t + 1 < SEQ) st_agent_u16(&hwrite[(size_t)m * HID + j], f2bf(hnew));
      if (layer == 0) {
        st_agent_u16(&p.out0[(((size_t)dir * SEQ + t) * BATCH + m) * HID + j], f2bf(hnew));
      } else {
        const int tt = dir ? (SEQ - 1 - t) : t;
        p.out[((size_t)m * SEQ + tt) * (2 * HID) + (size_t)dir * HID + j] = hnew;
      }
      if (t == SEQ - 1)
        hsec[((size_t)layer * BATCH + m) * (2 * HID) + (size_t)dir * HID + j] = hnew;
    }

    if (t + 1 < SEQ) {
      __syncthreads();  // all waves' stores drained (compiler: vmcnt(0) before s_barrier)
      if (threadIdx.x == 0) {
        __hip_atomic_fetch_add(cnt_own, 1, __ATOMIC_RELEASE, __HIP_MEMORY_SCOPE_AGENT);
        const int tgt_own = 32 * (t + 2);
        while (__hip_atomic_load(cnt_own, __ATOMIC_RELAXED, __HIP_MEMORY_SCOPE_AGENT) < tgt_own)
          __builtin_amdgcn_s_sleep(2);
        if (layer == 1) {  // next step reads out0[t+1]
          const int tgt_dep = 32 * (t + 3);
          while (__hip_atomic_load(cnt_dep, __ATOMIC_RELAXED, __HIP_MEMORY_SCOPE_AGENT) < tgt_dep)
            __builtin_amdgcn_s_sleep(2);
        }
      }
      __syncthreads();
    } else if (layer == 0) {
      // Final signal: layer-1's last dependency target is 32*(SEQ+1).
      // __syncthreads drains the out0[SEQ-1] stores before the release add.
      __syncthreads();
      if (threadIdx.x == 0)
        __hip_atomic_fetch_add(cnt_own, 1, __ATOMIC_RELEASE, __HIP_MEMORY_SCOPE_AGENT);
    }
  }
}

extern "C" void kernel_launch(void* const* d_in, const int* in_sizes, int n_in,
                              void* d_out, int out_size, void* d_ws, size_t ws_size,
                              hipStream_t stream) {
  Params p;
  p.input  = (const float*)d_in[0];
  p.enc_h  = (const float*)d_in[1];
  p.Wih[0] = (const float*)d_in[2];
  p.Whh[0] = (const float*)d_in[3];
  p.bih[0] = (const float*)d_in[4];
  p.bhh[0] = (const float*)d_in[5];
  p.Wih[1] = (const float*)d_in[6];
  p.Whh[1] = (const float*)d_in[7];
  p.bih[1] = (const float*)d_in[8];
  p.bhh[1] = (const float*)d_in[9];
  p.out = (float*)d_out;

  uintptr_t base = (uintptr_t)d_ws;
  size_t off = 0;
  auto take = [&](size_t bytes) -> void* {
    void* r = (void*)(base + off);
    off += (bytes + 255) & ~(size_t)255;
    return r;
  };
  p.xin  = (u16*)take((size_t)BATCH * SEQ * DIN * 2);        // 33.6 MB
  p.wih  = (u16*)take((size_t)2 * LAY * G3 * DIN * 2);       //  6.3 MB
  p.whh  = (u16*)take((size_t)2 * LAY * G3 * HID * 2);       //  6.3 MB
  p.out0 = (u16*)take((size_t)2 * SEQ * BATCH * HID * 2);    // 67.1 MB
  p.hbf  = (u16*)take((size_t)LAY * 2 * 2 * BATCH * HID * 2);//  1.0 MB
  p.cnt  = (int*)take(256);
  if (off > ws_size) return;  // ~114 MB required (same as passing R2 config)

  convert_kernel<<<dim3(2048), dim3(256), 0, stream>>>(p);
  recur_all<<<dim3(128), dim3(256), 0, stream>>>(p);
}

// Round 5
// 8097.482 us; speedup vs baseline: 2.5891x; 1.0667x over previous
//
#include <hip/hip_runtime.h>

// Problem dims (fixed)
constexpr int BATCH = 64;
constexpr int SEQ   = 512;
constexpr int DIN   = 512;
constexpr int HID   = 512;
constexpr int LAY   = 2;
constexpr int G3    = 3 * HID;   // 1536
constexpr int KPAD  = 522;       // odd dword stride (261) -> conflict-free LDS rows

typedef __attribute__((ext_vector_type(8))) short bf16x8;  // MFMA A/B frag (4 VGPRs)
typedef __attribute__((ext_vector_type(4))) float f32x4;   // MFMA C/D frag
typedef unsigned short u16;
typedef unsigned int   u32;
typedef unsigned long long u64;

__device__ __forceinline__ u16 f2bf(float f) {
  union { float f; u32 u; } v; v.f = f;
  return (u16)((v.u + 0x7fffu + ((v.u >> 16) & 1u)) >> 16);  // RNE
}

// Agent-scope RELAXED accesses: coherent at LLC (bypass non-coherent per-XCD
// L2), and crucially NO cache maintenance: no buffer_inv (acquire, R2 killer),
// no buffer_wbl2 (release, R4 killer). Visibility protocol: producer's agent
// stores are drained (vmcnt 0) by __syncthreads before the flag store; LLC is
// the single serialization point; consumer's loads issue after its poll branch
// resolves (waves issue vector-memory ops in order).
__device__ __forceinline__ u64 ld_agent_u64(const u16* p) {
  return __hip_atomic_load((const u64*)p, __ATOMIC_RELAXED, __HIP_MEMORY_SCOPE_AGENT);
}
__device__ __forceinline__ bf16x8 ld_frag_agent(const u16* p) {
  union { u64 q[2]; bf16x8 f; } u;
  u.q[0] = ld_agent_u64(p);
  u.q[1] = ld_agent_u64(p + 4);
  return u.f;
}
__device__ __forceinline__ void st_agent_u16(u16* p, u16 v) {
  __hip_atomic_store(p, v, __ATOMIC_RELAXED, __HIP_MEMORY_SCOPE_AGENT);
}
__device__ __forceinline__ void st_agent_u32(u32* p, u32 v) {
  __hip_atomic_store(p, v, __ATOMIC_RELAXED, __HIP_MEMORY_SCOPE_AGENT);
}

// Poll all 32 flags of a cell (one coalesced 128B load) until min >= target.
__device__ __forceinline__ void poll_ge(const u32* flags, u32 target) {
  const int idx = threadIdx.x & 31;
  for (;;) {
    u32 v = __hip_atomic_load(flags + idx, __ATOMIC_RELAXED, __HIP_MEMORY_SCOPE_AGENT);
    #pragma unroll
    for (int off = 16; off >= 1; off >>= 1) {
      u32 o = (u32)__shfl_xor((int)v, off, 64);
      v = v < o ? v : o;
    }
    if (v >= target) break;
    __builtin_amdgcn_s_sleep(1);
  }
  __asm__ volatile("" ::: "memory");  // keep subsequent loads after the poll
}

struct Params {
  const float* input;     // [BATCH][SEQ][DIN]
  const float* enc_h;     // [LAY][BATCH][2*HID]
  const float* Wih[2];    // dir f/b: [LAY][G3][DIN]
  const float* Whh[2];    // [LAY][G3][HID]
  const float* bih[2];    // [LAY][G3]
  const float* bhh[2];    // [LAY][G3]
  float* out;             // [BATCH][SEQ][2H] ++ [LAY][BATCH][2H]
  u16* xin;               // [BATCH][SEQ][DIN] bf16
  u16* wih;               // [2dir][LAY][G3][DIN] bf16
  u16* whh;               // [2dir][LAY][G3][HID] bf16
  u16* out0;              // [2dir][SEQ][BATCH][HID] bf16 layer-0 outputs (scan order)
  u16* hbf;               // [LAY][2 parity][2 dir][BATCH][HID] bf16 h broadcast
  u32* flags;             // [LAY][2dir][32] per-WG step flags (0=none,1=init,t+2=step t done)
};

__global__ __launch_bounds__(256) void convert_kernel(Params p) {
  const int gtid = blockIdx.x * 256 + threadIdx.x;
  const int nthr = gridDim.x * 256;
  for (int i = gtid; i < BATCH * SEQ * DIN; i += nthr) p.xin[i] = f2bf(p.input[i]);
  for (int d = 0; d < 2; ++d) {
    const float* s1 = p.Wih[d];
    u16* d1 = p.wih + (size_t)d * LAY * G3 * DIN;
    for (int i = gtid; i < LAY * G3 * DIN; i += nthr) d1[i] = f2bf(s1[i]);
    const float* s2 = p.Whh[d];
    u16* d2 = p.whh + (size_t)d * LAY * G3 * HID;
    for (int i = gtid; i < LAY * G3 * HID; i += nthr) d2[i] = f2bf(s2[i]);
  }
  if (gtid < LAY * 2 * 32) p.flags[gtid] = 0;
}

// 128 WGs: wg>>6 = layer (layer1 trails layer0 by one step), wg&1 = dir,
// (wg&63)>>1 = 16-wide hidden slice. 4 waves = 4 batch m-tiles of 16.
// h master fp32 in regs; bf16 double-buffered broadcast via LLC (agent ops).
// Whh slice LDS-resident; Wih/x L1+L2-cached (no cache maintenance anywhere).
// x-GEMM for step t+1 runs between signal(t) and poll(t) — barrier shadow.
__global__ __launch_bounds__(256, 1) void recur_all(Params p) {
  const int wg    = blockIdx.x;     // 0..127
  const int layer = wg >> 6;
  const int cwg   = wg & 63;
  const int dir   = cwg & 1;
  const int slice = cwg >> 1;       // 0..31
  const int j0    = slice * 16;
  const int wave  = threadIdx.x >> 6;
  const int lane  = threadIdx.x & 63;
  const int lq = lane >> 4, ln = lane & 15;
  const int j = j0 + ln;            // hidden column (C/D col = lane&15)

  // ---- stage Whh slice into LDS: [gate][jj][k] (odd-dword row stride) ----
  __shared__ u16 lwhh[3][16][KPAD];   // 50,112 B
  {
    const u16* whh = p.whh + ((size_t)dir * LAY + layer) * G3 * HID;
    for (int idx = threadIdx.x; idx < 3 * 16 * 64; idx += 256) {
      const int k8 = idx & 63, row = idx >> 6;     // row = g*16+jj
      const int g = row >> 4, jj = row & 15;
      *(bf16x8*)&lwhh[g][jj][k8 * 8] =
          *(const bf16x8*)(whh + (size_t)(g * HID + j0 + jj) * HID + k8 * 8);
    }
  }

  u16* hbL = p.hbf + (size_t)layer * 2 * 2 * BATCH * HID;
  u16* hb[2] = { hbL + (size_t)dir * BATCH * HID,
                 hbL + (size_t)(2 + dir) * BATCH * HID };

  const u16* wih = p.wih + ((size_t)dir * LAY + layer) * G3 * DIN;
  const u16* bri[3];
  #pragma unroll
  for (int g = 0; g < 3; ++g) bri[g] = wih + (size_t)(g * HID + j) * DIN;

  const float* bih = p.bih[dir] + (size_t)layer * G3;
  const float* bhh = p.bhh[dir] + (size_t)layer * G3;
  const float b_r  = bih[j] + bhh[j];
  const float b_z  = bih[HID + j] + bhh[HID + j];
  const float bi_n = bih[2 * HID + j];
  const float bh_n = bhh[2 * HID + j];

  // init h (fp32 master) + bf16 broadcast into parity 0 (agent-scope)
  float hreg[4];
  #pragma unroll
  for (int i = 0; i < 4; ++i) {
    const int m = wave * 16 + lq * 4 + i;       // C/D row = (lane>>4)*4 + reg
    hreg[i] = p.enc_h[((size_t)layer * BATCH + m) * (2 * HID) + (size_t)dir * HID + j];
    st_agent_u16(&hb[0][(size_t)m * HID + j], f2bf(hreg[i]));
  }

  u32* fown  = p.flags + (size_t)(layer * 2 + dir) * 32;
  u32* fdep  = p.flags + (size_t)dir * 32;      // layer-0's cell, same dir
  u32* fslot = fown + slice;

  __threadfence_block();   // vmcnt(0)/lgkmcnt(0): LDS staging + init stores drained
  __syncthreads();
  if (threadIdx.x == 0) st_agent_u32(fslot, 1);

  const int am = wave * 16 + ln;                // A-frag row (lane&15 within M-tile)
  float* hsec = p.out + (size_t)BATCH * SEQ * 2 * HID;

  // ---- precompute accx for step 0 (layer 1 must wait for out0[0] first) ----
  f32x4 accx[3];
  if (layer == 1) poll_ge(fdep, 2);
  {
    const u16* ax = (layer == 0)
        ? p.xin + ((size_t)am * SEQ + (dir ? SEQ - 1 : 0)) * DIN
        : p.out0 + ((size_t)dir * SEQ * BATCH + am) * HID;
    accx[0] = f32x4{0, 0, 0, 0}; accx[1] = accx[0]; accx[2] = accx[0];
    #pragma unroll 4
    for (int k0 = 0; k0 < 512; k0 += 32) {
      const int koff = k0 + lq * 8;
      const bf16x8 a_x = (layer == 0) ? *(const bf16x8*)(ax + koff)
                                      : ld_frag_agent(ax + koff);
      #pragma unroll
      for (int g = 0; g < 3; ++g)
        accx[g] = __builtin_amdgcn_mfma_f32_16x16x32_bf16(
            a_x, *(const bf16x8*)(bri[g] + koff), accx[g], 0, 0, 0);
    }
  }
  poll_ge(fown, 1);  // h_0 broadcast visible

  for (int t = 0; t < SEQ; ++t) {
    // ---- h-GEMM (critical path) ----
    const u16* ah = hb[t & 1] + (size_t)am * HID;
    f32x4 acch[3] = {};
    #pragma unroll 4
    for (int k0 = 0; k0 < 512; k0 += 32) {
      const int koff = k0 + lq * 8;
      const bf16x8 a_h = ld_frag_agent(ah + koff);
      #pragma unroll
      for (int g = 0; g < 3; ++g)
        acch[g] = __builtin_amdgcn_mfma_f32_16x16x32_bf16(
            a_h, *(const bf16x8*)&lwhh[g][ln][koff], acch[g], 0, 0, 0);
    }

    // ---- gate epilogue + stores ----
    u16* hwrite = hb[(t + 1) & 1];
    #pragma unroll
    for (int i = 0; i < 4; ++i) {
      const int m = wave * 16 + lq * 4 + i;
      const float r = 1.f / (1.f + __expf(-(accx[0][i] + acch[0][i] + b_r)));
      const float z = 1.f / (1.f + __expf(-(accx[1][i] + acch[1][i] + b_z)));
      const float n = tanhf(accx[2][i] + bi_n + r * (acch[2][i] + bh_n));
      const float hnew = (1.f - z) * n + z * hreg[i];
      hreg[i] = hnew;
      if (t + 1 < SEQ) st_agent_u16(&hwrite[(size_t)m * HID + j], f2bf(hnew));
      if (layer == 0) {
        st_agent_u16(&p.out0[(((size_t)dir * SEQ + t) * BATCH + m) * HID + j], f2bf(hnew));
      } else {
        const int tt = dir ? (SEQ - 1 - t) : t;
        p.out[((size_t)m * SEQ + tt) * (2 * HID) + (size_t)dir * HID + j] = hnew;
      }
      if (t == SEQ - 1)
        hsec[((size_t)layer * BATCH + m) * (2 * HID) + (size_t)dir * HID + j] = hnew;
    }

    // ---- signal: all this WG's stores drained, then flag (no RMW, no fence ops)
    __threadfence_block();
    __syncthreads();
    if (threadIdx.x == 0) st_agent_u32(fslot, (u32)(t + 2));

    if (t + 1 < SEQ) {
      // ---- x-GEMM for t+1 in the barrier shadow ----
      if (layer == 1) poll_ge(fdep, (u32)(t + 3));  // out0[t+1] ready
      const int tn = t + 1;
      const u16* ax = (layer == 0)
          ? p.xin + ((size_t)am * SEQ + (dir ? SEQ - 1 - tn : tn)) * DIN
          : p.out0 + (((size_t)dir * SEQ + tn) * BATCH + am) * HID;
      accx[0] = f32x4{0, 0, 0, 0}; accx[1] = accx[0]; accx[2] = accx[0];
      #pragma unroll 4
      for (int k0 = 0; k0 < 512; k0 += 32) {
        const int koff = k0 + lq * 8;
        const bf16x8 a_x = (layer == 0) ? *(const bf16x8*)(ax + koff)
                                        : ld_frag_agent(ax + koff);
        #pragma unroll
        for (int g = 0; g < 3; ++g)
          accx[g] = __builtin_amdgcn_mfma_f32_16x16x32_bf16(
              a_x, *(const bf16x8*)(bri[g] + koff), accx[g], 0, 0, 0);
      }
      poll_ge(fown, (u32)(t + 2));  // h_{t+1} broadcast visible
    }
  }
}

extern "C" void kernel_launch(void* const* d_in, const int* in_sizes, int n_in,
                              void* d_out, int out_size, void* d_ws, size_t ws_size,
                              hipStream_t stream) {
  Params p;
  p.input  = (const float*)d_in[0];
  p.enc_h  = (const float*)d_in[1];
  p.Wih[0] = (const float*)d_in[2];
  p.Whh[0] = (const float*)d_in[3];
  p.bih[0] = (const float*)d_in[4];
  p.bhh[0] = (const float*)d_in[5];
  p.Wih[1] = (const float*)d_in[6];
  p.Whh[1] = (const float*)d_in[7];
  p.bih[1] = (const float*)d_in[8];
  p.bhh[1] = (const float*)d_in[9];
  p.out = (float*)d_out;

  uintptr_t base = (uintptr_t)d_ws;
  size_t off = 0;
  auto take = [&](size_t bytes) -> void* {
    void* r = (void*)(base + off);
    off += (bytes + 255) & ~(size_t)255;
    return r;
  };
  p.xin   = (u16*)take((size_t)BATCH * SEQ * DIN * 2);        // 33.6 MB
  p.wih   = (u16*)take((size_t)2 * LAY * G3 * DIN * 2);       //  6.3 MB
  p.whh   = (u16*)take((size_t)2 * LAY * G3 * HID * 2);       //  6.3 MB
  p.out0  = (u16*)take((size_t)2 * SEQ * BATCH * HID * 2);    // 67.1 MB
  p.hbf   = (u16*)take((size_t)LAY * 2 * 2 * BATCH * HID * 2);//  1.0 MB
  p.flags = (u32*)take((size_t)LAY * 2 * 32 * 4);             //  512 B
  if (off > ws_size) return;  // ~114 MB required (same budget as R4)

  convert_kernel<<<dim3(2048), dim3(256), 0, stream>>>(p);
  recur_all<<<dim3(128), dim3(256), 0, stream>>>(p);
}